// Round 5
// baseline (4440.728 us; speedup 1.0000x reference)
//
#include <hip/hip_runtime.h>
#include <hip/hip_bf16.h>

typedef __attribute__((ext_vector_type(4))) int i32x4;
typedef __attribute__((ext_vector_type(8))) int i32x8;
typedef __attribute__((ext_vector_type(16))) float f32x16;

#define E4M3_MAX 448.0f
#define AS1 __attribute__((address_space(1)))
#define AS3 __attribute__((address_space(3)))

__device__ __forceinline__ float clip448(float v) {
  return fminf(fmaxf(v, -E4M3_MAX), E4M3_MAX);
}

__device__ __forceinline__ void gld_lds16(const void* g, void* l) {
  __builtin_amdgcn_global_load_lds((const AS1 void*)g, (AS3 void*)l, 16, 0, 0);
}

__device__ __forceinline__ float gelu_f(float v) {
  float y = 0.7978845608028654f * (v + 0.044715f * v * v * v);
  float a = fabsf(y);
  float z = __expf(-2.f * a);          // z in (0,1], no overflow
  float th = (1.f - z) / (1.f + z);    // tanh(|y|)
  th = copysignf(th, y);
  return 0.5f * v * (1.f + th);
}

// ---------------- init ----------------
__global__ void init_ws_kernel(unsigned int* amax) {
  amax[0] = 0u;
  amax[1] = 0u;
}

// ---------------- amax reduction ----------------
__global__ void amax_kernel(const float* __restrict__ x, long n4,
                            unsigned int* __restrict__ amax_out) {
  long i0 = (long)blockIdx.x * blockDim.x + threadIdx.x;
  long stride = (long)gridDim.x * blockDim.x;
  const float4* x4 = (const float4*)x;
  float m = 0.f;
  for (long i = i0; i < n4; i += stride) {
    float4 v = x4[i];
    m = fmaxf(m, fmaxf(fmaxf(fabsf(v.x), fabsf(v.y)), fmaxf(fabsf(v.z), fabsf(v.w))));
  }
#pragma unroll
  for (int off = 32; off >= 1; off >>= 1)
    m = fmaxf(m, __shfl_xor(m, off));
  __shared__ float wmax[8];
  int wid = threadIdx.x >> 6;
  if ((threadIdx.x & 63) == 0) wmax[wid] = m;
  __syncthreads();
  if (threadIdx.x == 0) {
    int nw = blockDim.x >> 6;
    float bm = wmax[0];
    for (int w = 1; w < nw; ++w) bm = fmaxf(bm, wmax[w]);
    atomicMax(amax_out, __float_as_uint(bm));  // vals >= 0: uint order == float order
  }
}

// ---------------- delayed-scaling scale computation ----------------
__global__ void scale_kernel(const unsigned int* __restrict__ amax,
                             const float* __restrict__ scale_x,
                             const float* __restrict__ hist_x,
                             const float* __restrict__ scale_k,
                             const float* __restrict__ hist_k,
                             int hl, float* __restrict__ scales) {
  if (threadIdx.x != 0) return;
  float ax = __uint_as_float(amax[0]);
  for (int i = 0; i < hl - 1; ++i) ax = fmaxf(ax, hist_x[i]);
  float sfx = E4M3_MAX / ax;
  if (!(ax > 0.f && isfinite(ax))) sfx = 1.f / scale_x[0];
  float sx = 1.f / sfx;
  float ak = __uint_as_float(amax[1]);
  for (int i = 0; i < hl - 1; ++i) ak = fmaxf(ak, hist_k[i]);
  float sfk = E4M3_MAX / ak;
  if (!(ak > 0.f && isfinite(ak))) sfk = 1.f / scale_k[0];
  float sk = 1.f / sfk;
  scales[0] = sx;
  scales[1] = sk;
  scales[2] = sx * sk;
}

// Tile layout (both operands), matched to mfma_scale_f32_32x32x64_f8f6f4:
// per (row-block 128 × k-block 64) tile, 8192 B contiguous, as 512 16-B
// chunks c = g*128 + h*64 + l  (g=row-group 0..3, h=k-half 0..1, l=lane):
//   chunk holds op[row = g*32 + (l&31)][k = (l>>5)*32 + h*16 + 0..15]
// => GEMM stages linearly with global_load_lds and reads each lane's
//    32-byte fragment as two conflict-free ds_read_b128 at lane*16.

// ---------------- quantize x -> tiled fp8 A ----------------
__global__ void quant_x_kernel(const float* __restrict__ x,
                               unsigned char* __restrict__ Aq,
                               const float* __restrict__ scales, int K) {
  const float s = scales[0];
  const int kt = blockIdx.x, mt = blockIdx.y, nkt = gridDim.x;
  __shared__ float lt[128][68];
  const int t = threadIdx.x;
  const float* src = x + (size_t)mt * 128 * K + (size_t)kt * 64;
#pragma unroll
  for (int it = 0; it < 8; ++it) {
    int row = it * 16 + (t >> 4);
    int c4 = (t & 15) * 4;
    float4 v = *(const float4*)&src[(size_t)row * K + c4];
    lt[row][c4 + 0] = v.x; lt[row][c4 + 1] = v.y;
    lt[row][c4 + 2] = v.z; lt[row][c4 + 3] = v.w;
  }
  __syncthreads();
  uint4* out = (uint4*)(Aq + ((size_t)mt * nkt + kt) * 8192);
#pragma unroll
  for (int cc = 0; cc < 2; ++cc) {
    int c = t * 2 + cc;
    int g = c >> 7, h = (c >> 6) & 1, l = c & 63;
    int row = g * 32 + (l & 31);
    int kb = (l >> 5) * 32 + h * 16;
    unsigned int w[4];
#pragma unroll
    for (int q = 0; q < 4; ++q) {
      int b = kb + q * 4;
      int p = 0;
      p = __builtin_amdgcn_cvt_pk_fp8_f32(clip448(lt[row][b+0] / s), clip448(lt[row][b+1] / s), p, false);
      p = __builtin_amdgcn_cvt_pk_fp8_f32(clip448(lt[row][b+2] / s), clip448(lt[row][b+3] / s), p, true);
      w[q] = (unsigned int)p;
    }
    out[c] = make_uint4(w[0], w[1], w[2], w[3]);
  }
}

// ---------------- transpose-quantize W[K][N] -> tiled fp8 B ----------------
__global__ void quant_k_kernel(const float* __restrict__ w,
                               unsigned char* __restrict__ Bq,
                               const float* __restrict__ scales, int N) {
  const float s = scales[1];
  const int kt = blockIdx.x, nt = blockIdx.y, nkt = gridDim.x;
  __shared__ float lt[64][132];
  const int t = threadIdx.x;
  const float* src = w + (size_t)kt * 64 * N + (size_t)nt * 128;
#pragma unroll
  for (int it = 0; it < 8; ++it) {
    int row = it * 8 + (t >> 5);
    int c4 = (t & 31) * 4;
    float4 v = *(const float4*)&src[(size_t)row * N + c4];
    lt[row][c4 + 0] = v.x; lt[row][c4 + 1] = v.y;
    lt[row][c4 + 2] = v.z; lt[row][c4 + 3] = v.w;
  }
  __syncthreads();
  uint4* out = (uint4*)(Bq + ((size_t)nt * nkt + kt) * 8192);
#pragma unroll
  for (int cc = 0; cc < 2; ++cc) {
    int c = t * 2 + cc;
    int g = c >> 7, h = (c >> 6) & 1, l = c & 63;
    int nl = g * 32 + (l & 31);
    int kb = (l >> 5) * 32 + h * 16;
    unsigned int w4[4];
#pragma unroll
    for (int q = 0; q < 4; ++q) {
      int b = kb + q * 4;
      int p = 0;
      p = __builtin_amdgcn_cvt_pk_fp8_f32(clip448(lt[b+0][nl] / s), clip448(lt[b+1][nl] / s), p, false);
      p = __builtin_amdgcn_cvt_pk_fp8_f32(clip448(lt[b+2][nl] / s), clip448(lt[b+3][nl] / s), p, true);
      w4[q] = (unsigned int)p;
    }
    out[c] = make_uint4(w4[0], w4[1], w4[2], w4[3]);
  }
}

// ---------------- MX fp8 GEMM + scale + bias + gelu ----------------
// 256x256 tile, BK=64, 512 threads (8 waves, 2Mx4N of 128x64 per wave).
// 3-buffer LDS + register-prefetched fragments: MFMA(tile kt) overlaps
// ds_read(tile kt+1) and global_load_lds(tile kt+2) with counted vmcnt.
#define LDSBUF 32768

struct Frags {
  i32x8 av[4];
  i32x8 bv[2];
};

__global__ __launch_bounds__(512, 2) void gemm_fp8_kernel(
    const unsigned char* __restrict__ Aq, const unsigned char* __restrict__ Bq,
    const float* __restrict__ bias, const float* __restrict__ scales,
    float* __restrict__ C, int M, int N, int K) {
  __shared__ __align__(16) unsigned char lds[3 * LDSBUF];  // 96 KB
  const float s_xk = scales[2];
  const int nkt = K >> 6;
  const int t = threadIdx.x;
  const int lane = t & 63;
  const int wid = t >> 6;
  const int wm = wid >> 2, wn = wid & 3;

  // XCD-aware bijective swizzle (nwg = 2048, divisible by 8)
  int f = blockIdx.y * gridDim.x + blockIdx.x;
  int cpx = (gridDim.x * gridDim.y) >> 3;
  int f2 = (f & 7) * cpx + (f >> 3);
  int bx = f2 % gridDim.x;
  int by = f2 / gridDim.x;

  const size_t strideT = (size_t)nkt * 8192;  // one 128-row tile stream
  const unsigned char* gA = Aq + (size_t)(2 * by) * strideT + t * 16;
  const unsigned char* gB = Bq + (size_t)(2 * bx) * strideT + t * 16;

  f32x16 acc[4][2];
#pragma unroll
  for (int i = 0; i < 4; ++i)
#pragma unroll
    for (int j = 0; j < 2; ++j)
#pragma unroll
      for (int r = 0; r < 16; ++r) acc[i][j][r] = 0.f;

  auto stage = [&](int b, int kt_) {
    size_t o = (size_t)kt_ * 8192;
    unsigned char* l = lds + b * LDSBUF + wid * 1024;
    gld_lds16(gA + o,           l);
    gld_lds16(gA + strideT + o, l + 8192);
    gld_lds16(gB + o,           l + 16384);
    gld_lds16(gB + strideT + o, l + 24576);
  };

  auto read_frags = [&](Frags& fr, int b) {
    const unsigned char* la = lds + b * LDSBUF;
    const unsigned char* lb = la + 16384;
#pragma unroll
    for (int i = 0; i < 4; ++i) {
      int g = wm * 4 + i;
      *(i32x4*)&fr.av[i]       = *(const i32x4*)&la[g * 2048 + lane * 16];
      *(((i32x4*)&fr.av[i])+1) = *(const i32x4*)&la[g * 2048 + 1024 + lane * 16];
    }
#pragma unroll
    for (int j = 0; j < 2; ++j) {
      int g = wn * 2 + j;
      *(i32x4*)&fr.bv[j]       = *(const i32x4*)&lb[g * 2048 + lane * 16];
      *(((i32x4*)&fr.bv[j])+1) = *(const i32x4*)&lb[g * 2048 + 1024 + lane * 16];
    }
  };

  auto mfma_all = [&](const Frags& fr) {
    __builtin_amdgcn_s_setprio(1);
#pragma unroll
    for (int i = 0; i < 4; ++i)
#pragma unroll
      for (int j = 0; j < 2; ++j)
        acc[i][j] = __builtin_amdgcn_mfma_scale_f32_32x32x64_f8f6f4(
            fr.av[i], fr.bv[j], acc[i][j], 0, 0, 0, 127, 0, 127);
    __builtin_amdgcn_s_setprio(0);
  };

  Frags fA, fB;

  // prologue: stage tiles 0,1; read frags(tile0)
  stage(0, 0);
  stage(1, 1);
  asm volatile("s_waitcnt vmcnt(4)" ::: "memory");  // tile0 landed
  __builtin_amdgcn_s_barrier();
  read_frags(fA, 0);
  asm volatile("s_waitcnt lgkmcnt(0)" ::: "memory");

  int kt = 0;
  for (; kt + 1 < nkt; kt += 2) {
    // EVEN: compute fA (tile kt); prefetch fB <- tile kt+1; stage tile kt+2
    if (kt + 2 < nkt) {
      stage((kt + 2) % 3, kt + 2);
      asm volatile("s_waitcnt vmcnt(4)" ::: "memory");  // tile kt+1 landed
    } else {
      asm volatile("s_waitcnt vmcnt(0)" ::: "memory");
    }
    __builtin_amdgcn_s_barrier();
    read_frags(fB, (kt + 1) % 3);
    mfma_all(fA);  // independent of fB reads -> overlap
    asm volatile("s_waitcnt lgkmcnt(0)" ::: "memory");

    // ODD: compute fB (tile kt+1); prefetch fA <- tile kt+2; stage tile kt+3
    if (kt + 3 < nkt) {
      stage((kt + 3) % 3, kt + 3);
      asm volatile("s_waitcnt vmcnt(4)" ::: "memory");  // tile kt+2 landed
    } else {
      asm volatile("s_waitcnt vmcnt(0)" ::: "memory");
    }
    __builtin_amdgcn_s_barrier();
    if (kt + 2 < nkt) read_frags(fA, (kt + 2) % 3);
    mfma_all(fB);
    asm volatile("s_waitcnt lgkmcnt(0)" ::: "memory");
  }
  if (kt < nkt) {  // odd nkt tail (unused for K=4096)
    mfma_all(fA);
  }

  // epilogue: scale, bias (bf16-rounded), fast tanh-gelu, nontemporal store
  const int m0 = by * 256;
  const int n0 = bx * 256;
  float bb[2];
#pragma unroll
  for (int j = 0; j < 2; ++j) {
    int col = n0 + wn * 64 + j * 32 + (lane & 31);
    bb[j] = __bfloat162float(__float2bfloat16(bias[col]));
  }
#pragma unroll
  for (int i = 0; i < 4; ++i) {
    int rowbase = m0 + wm * 128 + i * 32 + 4 * (lane >> 5);
#pragma unroll
    for (int j = 0; j < 2; ++j) {
      int col = n0 + wn * 64 + j * 32 + (lane & 31);
#pragma unroll
      for (int r = 0; r < 16; ++r) {
        int row = rowbase + (r & 3) + 8 * (r >> 2);
        float v = acc[i][j][r] * s_xk + bb[j];
        __builtin_nontemporal_store(gelu_f(v), &C[(size_t)row * N + col]);
      }
    }
  }
}

// ---------------- launch ----------------
extern "C" void kernel_launch(void* const* d_in, const int* in_sizes, int n_in,
                              void* d_out, int out_size, void* d_ws, size_t ws_size,
                              hipStream_t stream) {
  const float* inputs = (const float*)d_in[0];
  const float* kernelw = (const float*)d_in[1];
  const float* bias = (const float*)d_in[2];
  const float* input_scale = (const float*)d_in[3];
  const float* input_hist = (const float*)d_in[4];
  const float* kernel_scale = (const float*)d_in[5];
  const float* kernel_hist = (const float*)d_in[6];

  const int F = in_sizes[2];             // 16384
  const int D = in_sizes[1] / F;         // 4096
  const long M = (long)in_sizes[0] / D;  // 8192
  const int HL = in_sizes[4];            // 16
  const int N = F, K = D;

  unsigned int* amax = (unsigned int*)d_ws;
  float* scales = (float*)((char*)d_ws + 16);
  unsigned char* Aq = (unsigned char*)d_ws + 64;
  unsigned char* Bq = Aq + (size_t)M * K;

  float* C = (float*)d_out;

  init_ws_kernel<<<1, 1, 0, stream>>>(amax);
  amax_kernel<<<2048, 256, 0, stream>>>(inputs, (long)M * K / 4, &amax[0]);
  amax_kernel<<<2048, 256, 0, stream>>>(kernelw, (long)K * N / 4, &amax[1]);
  scale_kernel<<<1, 64, 0, stream>>>(amax, input_scale, input_hist, kernel_scale,
                                     kernel_hist, HL, scales);
  quant_x_kernel<<<dim3(K / 64, M / 128), 256, 0, stream>>>(inputs, Aq, scales, K);
  quant_k_kernel<<<dim3(K / 64, N / 128), 256, 0, stream>>>(kernelw, Bq, scales, N);
  gemm_fp8_kernel<<<dim3(N / 256, M / 256), 512, 0, stream>>>(Aq, Bq, bias, scales, C,
                                                              (int)M, N, K);
}

// Round 6
// 974.085 us; speedup vs baseline: 4.5589x; 4.5589x over previous
//
#include <hip/hip_runtime.h>
#include <hip/hip_bf16.h>

typedef __attribute__((ext_vector_type(4))) int i32x4;
typedef __attribute__((ext_vector_type(8))) int i32x8;
typedef __attribute__((ext_vector_type(16))) float f32x16;

#define E4M3_MAX 448.0f
#define AS1 __attribute__((address_space(1)))
#define AS3 __attribute__((address_space(3)))

__device__ __forceinline__ float clip448(float v) {
  return fminf(fmaxf(v, -E4M3_MAX), E4M3_MAX);
}

__device__ __forceinline__ void gld_lds16(const void* g, void* l) {
  __builtin_amdgcn_global_load_lds((const AS1 void*)g, (AS3 void*)l, 16, 0, 0);
}

__device__ __forceinline__ float gelu_f(float v) {
  float y = 0.7978845608028654f * (v + 0.044715f * v * v * v);
  float a = fabsf(y);
  float z = __expf(-2.f * a);          // z in (0,1], no overflow
  float th = (1.f - z) / (1.f + z);    // tanh(|y|)
  th = copysignf(th, y);
  return 0.5f * v * (1.f + th);
}

// ---------------- init ----------------
__global__ void init_ws_kernel(unsigned int* amax) {
  amax[0] = 0u;
  amax[1] = 0u;
}

// ---------------- amax reduction ----------------
__global__ void amax_kernel(const float* __restrict__ x, long n4,
                            unsigned int* __restrict__ amax_out) {
  long i0 = (long)blockIdx.x * blockDim.x + threadIdx.x;
  long stride = (long)gridDim.x * blockDim.x;
  const float4* x4 = (const float4*)x;
  float m = 0.f;
  for (long i = i0; i < n4; i += stride) {
    float4 v = x4[i];
    m = fmaxf(m, fmaxf(fmaxf(fabsf(v.x), fabsf(v.y)), fmaxf(fabsf(v.z), fabsf(v.w))));
  }
#pragma unroll
  for (int off = 32; off >= 1; off >>= 1)
    m = fmaxf(m, __shfl_xor(m, off));
  __shared__ float wmax[8];
  int wid = threadIdx.x >> 6;
  if ((threadIdx.x & 63) == 0) wmax[wid] = m;
  __syncthreads();
  if (threadIdx.x == 0) {
    int nw = blockDim.x >> 6;
    float bm = wmax[0];
    for (int w = 1; w < nw; ++w) bm = fmaxf(bm, wmax[w]);
    atomicMax(amax_out, __float_as_uint(bm));  // vals >= 0: uint order == float order
  }
}

// ---------------- delayed-scaling scale computation ----------------
__global__ void scale_kernel(const unsigned int* __restrict__ amax,
                             const float* __restrict__ scale_x,
                             const float* __restrict__ hist_x,
                             const float* __restrict__ scale_k,
                             const float* __restrict__ hist_k,
                             int hl, float* __restrict__ scales) {
  if (threadIdx.x != 0) return;
  float ax = __uint_as_float(amax[0]);
  for (int i = 0; i < hl - 1; ++i) ax = fmaxf(ax, hist_x[i]);
  float sfx = E4M3_MAX / ax;
  if (!(ax > 0.f && isfinite(ax))) sfx = 1.f / scale_x[0];
  float sx = 1.f / sfx;
  float ak = __uint_as_float(amax[1]);
  for (int i = 0; i < hl - 1; ++i) ak = fmaxf(ak, hist_k[i]);
  float sfk = E4M3_MAX / ak;
  if (!(ak > 0.f && isfinite(ak))) sfk = 1.f / scale_k[0];
  float sk = 1.f / sfk;
  scales[0] = sx;
  scales[1] = sk;
  scales[2] = sx * sk;
}

// Tile layout (both operands), matched to mfma_scale_f32_32x32x64_f8f6f4:
// per (row-block 128 × k-block 64) tile, 8192 B contiguous, as 512 16-B
// chunks c = g*128 + h*64 + l  (g=row-group 0..3, h=k-half 0..1, l=lane):
//   chunk holds op[row = g*32 + (l&31)][k = (l>>5)*32 + h*16 + 0..15]
// => GEMM stages linearly with global_load_lds and reads each lane's
//    32-byte fragment as two conflict-free ds_read_b128 at lane*16.

// ---------------- quantize x -> tiled fp8 A ----------------
__global__ void quant_x_kernel(const float* __restrict__ x,
                               unsigned char* __restrict__ Aq,
                               const float* __restrict__ scales, int K) {
  const float s = scales[0];
  const int kt = blockIdx.x, mt = blockIdx.y, nkt = gridDim.x;
  __shared__ float lt[128][68];
  const int t = threadIdx.x;
  const float* src = x + (size_t)mt * 128 * K + (size_t)kt * 64;
#pragma unroll
  for (int it = 0; it < 8; ++it) {
    int row = it * 16 + (t >> 4);
    int c4 = (t & 15) * 4;
    float4 v = *(const float4*)&src[(size_t)row * K + c4];
    lt[row][c4 + 0] = v.x; lt[row][c4 + 1] = v.y;
    lt[row][c4 + 2] = v.z; lt[row][c4 + 3] = v.w;
  }
  __syncthreads();
  uint4* out = (uint4*)(Aq + ((size_t)mt * nkt + kt) * 8192);
#pragma unroll
  for (int cc = 0; cc < 2; ++cc) {
    int c = t * 2 + cc;
    int g = c >> 7, h = (c >> 6) & 1, l = c & 63;
    int row = g * 32 + (l & 31);
    int kb = (l >> 5) * 32 + h * 16;
    unsigned int w[4];
#pragma unroll
    for (int q = 0; q < 4; ++q) {
      int b = kb + q * 4;
      int p = 0;
      p = __builtin_amdgcn_cvt_pk_fp8_f32(clip448(lt[row][b+0] / s), clip448(lt[row][b+1] / s), p, false);
      p = __builtin_amdgcn_cvt_pk_fp8_f32(clip448(lt[row][b+2] / s), clip448(lt[row][b+3] / s), p, true);
      w[q] = (unsigned int)p;
    }
    out[c] = make_uint4(w[0], w[1], w[2], w[3]);
  }
}

// ---------------- transpose-quantize W[K][N] -> tiled fp8 B ----------------
__global__ void quant_k_kernel(const float* __restrict__ w,
                               unsigned char* __restrict__ Bq,
                               const float* __restrict__ scales, int N) {
  const float s = scales[1];
  const int kt = blockIdx.x, nt = blockIdx.y, nkt = gridDim.x;
  __shared__ float lt[64][132];
  const int t = threadIdx.x;
  const float* src = w + (size_t)kt * 64 * N + (size_t)nt * 128;
#pragma unroll
  for (int it = 0; it < 8; ++it) {
    int row = it * 8 + (t >> 5);
    int c4 = (t & 31) * 4;
    float4 v = *(const float4*)&src[(size_t)row * N + c4];
    lt[row][c4 + 0] = v.x; lt[row][c4 + 1] = v.y;
    lt[row][c4 + 2] = v.z; lt[row][c4 + 3] = v.w;
  }
  __syncthreads();
  uint4* out = (uint4*)(Bq + ((size_t)nt * nkt + kt) * 8192);
#pragma unroll
  for (int cc = 0; cc < 2; ++cc) {
    int c = t * 2 + cc;
    int g = c >> 7, h = (c >> 6) & 1, l = c & 63;
    int nl = g * 32 + (l & 31);
    int kb = (l >> 5) * 32 + h * 16;
    unsigned int w4[4];
#pragma unroll
    for (int q = 0; q < 4; ++q) {
      int b = kb + q * 4;
      int p = 0;
      p = __builtin_amdgcn_cvt_pk_fp8_f32(clip448(lt[b+0][nl] / s), clip448(lt[b+1][nl] / s), p, false);
      p = __builtin_amdgcn_cvt_pk_fp8_f32(clip448(lt[b+2][nl] / s), clip448(lt[b+3][nl] / s), p, true);
      w4[q] = (unsigned int)p;
    }
    out[c] = make_uint4(w4[0], w4[1], w4[2], w4[3]);
  }
}

// ---------------- MX fp8 GEMM + scale + bias + gelu ----------------
// 256M x 128N tile, BK=64, 512 threads (8 waves, 2M x 4N; per-wave 128x32).
// 2-buffer LDS; register-prefetched fragments: MFMA(tile kt) overlaps
// ds_read(frags kt+1) and counted-vmcnt staging of tile kt+2.
// SPILL-SAFE: frags are plain locals built via shufflevector — never
// address-taken (round-5 lesson: pointer-cast writes into vector locals
// force scratch allocation -> 21 GB of spill traffic).
#define BUFSZ 24576  // 16 KB A (2x 128-row subtiles) + 8 KB B

#define RD_FRAGS(av, bv, bufbase)                                              \
  {                                                                            \
    const unsigned char* la_ = lds + (bufbase);                                \
    _Pragma("unroll") for (int i_ = 0; i_ < 4; ++i_) {                         \
      int g_ = wm * 4 + i_;                                                    \
      const unsigned char* p_ =                                                \
          la_ + (g_ >> 2) * 8192 + (g_ & 3) * 2048 + lane * 16;                \
      i32x4 lo_ = *(const i32x4*)p_;                                           \
      i32x4 hi_ = *(const i32x4*)(p_ + 1024);                                  \
      av[i_] = __builtin_shufflevector(lo_, hi_, 0, 1, 2, 3, 4, 5, 6, 7);      \
    }                                                                          \
    {                                                                          \
      const unsigned char* p_ = la_ + 16384 + wn * 2048 + lane * 16;           \
      i32x4 lo_ = *(const i32x4*)p_;                                           \
      i32x4 hi_ = *(const i32x4*)(p_ + 1024);                                  \
      bv = __builtin_shufflevector(lo_, hi_, 0, 1, 2, 3, 4, 5, 6, 7);          \
    }                                                                          \
  }

#define MFMA_ALL(av, bv)                                                       \
  {                                                                            \
    __builtin_amdgcn_s_setprio(1);                                             \
    _Pragma("unroll") for (int i_ = 0; i_ < 4; ++i_)                           \
        acc[i_] = __builtin_amdgcn_mfma_scale_f32_32x32x64_f8f6f4(             \
            av[i_], bv, acc[i_], 0, 0, 0, 127, 0, 127);                        \
    __builtin_amdgcn_s_setprio(0);                                             \
  }

__global__ __launch_bounds__(512, 2) void gemm_fp8_kernel(
    const unsigned char* __restrict__ Aq, const unsigned char* __restrict__ Bq,
    const float* __restrict__ bias, const float* __restrict__ scales,
    float* __restrict__ C, int M, int N, int K) {
  __shared__ __align__(16) unsigned char lds[2 * BUFSZ];  // 48 KB
  const float s_xk = scales[2];
  const int nkt = K >> 6;  // assumed even, >= 2 (K = 4096 here)
  const int t = threadIdx.x;
  const int lane = t & 63;
  const int wid = t >> 6;
  const int wm = wid >> 2, wn = wid & 3;

  // XCD-aware bijective swizzle (nwg = 4096, divisible by 8)
  int f = blockIdx.y * gridDim.x + blockIdx.x;
  int cpx = (gridDim.x * gridDim.y) >> 3;
  int f2 = (f & 7) * cpx + (f >> 3);
  int bx = f2 % gridDim.x;
  int by = f2 / gridDim.x;

  const size_t strideT = (size_t)nkt * 8192;  // one 128-row tile stream
  const unsigned char* gA = Aq + (size_t)(2 * by) * strideT + t * 16;
  const unsigned char* gB = Bq + (size_t)bx * strideT + t * 16;

  f32x16 acc[4];
#pragma unroll
  for (int i = 0; i < 4; ++i)
#pragma unroll
    for (int r = 0; r < 16; ++r) acc[i][r] = 0.f;

  auto stage = [&](unsigned bufbase, int kt_) {
    size_t o = (size_t)kt_ * 8192;
    unsigned char* l = lds + bufbase + wid * 1024;
    gld_lds16(gA + o,           l);            // A rows 0-127
    gld_lds16(gA + strideT + o, l + 8192);     // A rows 128-255
    gld_lds16(gB + o,           l + 16384);    // B rows 0-127
  };

  i32x8 avA[4], avB[4];
  i32x8 bvA, bvB;

  // prologue: stage tiles 0,1; read frags(tile 0)
  stage(0, 0);
  stage(BUFSZ, 1);
  asm volatile("s_waitcnt vmcnt(3)" ::: "memory");  // tile0's 3 landed
  __builtin_amdgcn_s_barrier();
  RD_FRAGS(avA, bvA, 0);
  asm volatile("s_waitcnt lgkmcnt(0)" ::: "memory");

  for (int kt = 0; kt + 1 < nkt; kt += 2) {
    // ---- tile kt (fA); prefetch fB <- tile kt+1; stage kt+2 -> buf0
    __builtin_amdgcn_s_barrier();  // all waves done reading buf0 (tile kt frags)
    if (kt + 2 < nkt) {
      stage(0, kt + 2);
      asm volatile("s_waitcnt vmcnt(3)" ::: "memory");  // tile kt+1 landed
    } else {
      asm volatile("s_waitcnt vmcnt(0)" ::: "memory");
    }
    __builtin_amdgcn_s_barrier();  // tile kt+1 visible to all waves
    RD_FRAGS(avB, bvB, BUFSZ);
    MFMA_ALL(avA, bvA);            // register-only: overlaps the ds_reads
    asm volatile("s_waitcnt lgkmcnt(0)" ::: "memory");

    // ---- tile kt+1 (fB); prefetch fA <- tile kt+2; stage kt+3 -> buf1
    __builtin_amdgcn_s_barrier();  // all waves done reading buf1
    if (kt + 3 < nkt) {
      stage(BUFSZ, kt + 3);
      asm volatile("s_waitcnt vmcnt(3)" ::: "memory");  // tile kt+2 landed
    } else {
      asm volatile("s_waitcnt vmcnt(0)" ::: "memory");
    }
    __builtin_amdgcn_s_barrier();
    if (kt + 2 < nkt) { RD_FRAGS(avA, bvA, 0); }
    MFMA_ALL(avB, bvB);
    asm volatile("s_waitcnt lgkmcnt(0)" ::: "memory");
  }

  // epilogue: scale, bias (bf16-rounded), fast tanh-gelu, nontemporal store
  const int m0 = by * 256;
  const int n0 = bx * 128;
  const int col = n0 + wn * 32 + (lane & 31);
  const float bb = __bfloat162float(__float2bfloat16(bias[col]));
#pragma unroll
  for (int i = 0; i < 4; ++i) {
    int rowbase = m0 + wm * 128 + i * 32 + 4 * (lane >> 5);
#pragma unroll
    for (int r = 0; r < 16; ++r) {
      int row = rowbase + (r & 3) + 8 * (r >> 2);
      float v = acc[i][r] * s_xk + bb;
      __builtin_nontemporal_store(gelu_f(v), &C[(size_t)row * N + col]);
    }
  }
}

// ---------------- launch ----------------
extern "C" void kernel_launch(void* const* d_in, const int* in_sizes, int n_in,
                              void* d_out, int out_size, void* d_ws, size_t ws_size,
                              hipStream_t stream) {
  const float* inputs = (const float*)d_in[0];
  const float* kernelw = (const float*)d_in[1];
  const float* bias = (const float*)d_in[2];
  const float* input_scale = (const float*)d_in[3];
  const float* input_hist = (const float*)d_in[4];
  const float* kernel_scale = (const float*)d_in[5];
  const float* kernel_hist = (const float*)d_in[6];

  const int F = in_sizes[2];             // 16384
  const int D = in_sizes[1] / F;         // 4096
  const long M = (long)in_sizes[0] / D;  // 8192
  const int HL = in_sizes[4];            // 16
  const int N = F, K = D;

  unsigned int* amax = (unsigned int*)d_ws;
  float* scales = (float*)((char*)d_ws + 16);
  unsigned char* Aq = (unsigned char*)d_ws + 64;
  unsigned char* Bq = Aq + (size_t)M * K;

  float* C = (float*)d_out;

  init_ws_kernel<<<1, 1, 0, stream>>>(amax);
  amax_kernel<<<2048, 256, 0, stream>>>(inputs, (long)M * K / 4, &amax[0]);
  amax_kernel<<<2048, 256, 0, stream>>>(kernelw, (long)K * N / 4, &amax[1]);
  scale_kernel<<<1, 64, 0, stream>>>(amax, input_scale, input_hist, kernel_scale,
                                     kernel_hist, HL, scales);
  quant_x_kernel<<<dim3(K / 64, M / 128), 256, 0, stream>>>(inputs, Aq, scales, K);
  quant_k_kernel<<<dim3(K / 64, N / 128), 256, 0, stream>>>(kernelw, Bq, scales, N);
  gemm_fp8_kernel<<<dim3(N / 128, M / 256), 512, 0, stream>>>(Aq, Bq, bias, scales, C,
                                                              (int)M, N, K);
}

// Round 7
// 756.487 us; speedup vs baseline: 5.8702x; 1.2876x over previous
//
#include <hip/hip_runtime.h>
#include <hip/hip_bf16.h>

typedef __attribute__((ext_vector_type(4))) int i32x4;
typedef __attribute__((ext_vector_type(8))) int i32x8;
typedef __attribute__((ext_vector_type(16))) float f32x16;

#define E4M3_MAX 448.0f
#define AS1 __attribute__((address_space(1)))
#define AS3 __attribute__((address_space(3)))

__device__ __forceinline__ float clip448(float v) {
  return fminf(fmaxf(v, -E4M3_MAX), E4M3_MAX);
}

__device__ __forceinline__ void gld_lds16(const void* g, void* l) {
  __builtin_amdgcn_global_load_lds((const AS1 void*)g, (AS3 void*)l, 16, 0, 0);
}

__device__ __forceinline__ float gelu_f(float v) {
  float y = 0.7978845608028654f * (v + 0.044715f * v * v * v);
  float a = fabsf(y);
  float z = __expf(-2.f * a);          // z in (0,1], no overflow
  float th = (1.f - z) / (1.f + z);    // tanh(|y|)
  th = copysignf(th, y);
  return 0.5f * v * (1.f + th);
}

// ---------------- init ----------------
__global__ void init_ws_kernel(unsigned int* amax) {
  amax[0] = 0u;
  amax[1] = 0u;
}

// ---------------- amax reduction ----------------
__global__ void amax_kernel(const float* __restrict__ x, long n4,
                            unsigned int* __restrict__ amax_out) {
  long i0 = (long)blockIdx.x * blockDim.x + threadIdx.x;
  long stride = (long)gridDim.x * blockDim.x;
  const float4* x4 = (const float4*)x;
  float m = 0.f;
  for (long i = i0; i < n4; i += stride) {
    float4 v = x4[i];
    m = fmaxf(m, fmaxf(fmaxf(fabsf(v.x), fabsf(v.y)), fmaxf(fabsf(v.z), fabsf(v.w))));
  }
#pragma unroll
  for (int off = 32; off >= 1; off >>= 1)
    m = fmaxf(m, __shfl_xor(m, off));
  __shared__ float wmax[8];
  int wid = threadIdx.x >> 6;
  if ((threadIdx.x & 63) == 0) wmax[wid] = m;
  __syncthreads();
  if (threadIdx.x == 0) {
    int nw = blockDim.x >> 6;
    float bm = wmax[0];
    for (int w = 1; w < nw; ++w) bm = fmaxf(bm, wmax[w]);
    atomicMax(amax_out, __float_as_uint(bm));  // vals >= 0: uint order == float order
  }
}

// ---------------- delayed-scaling scale computation ----------------
__global__ void scale_kernel(const unsigned int* __restrict__ amax,
                             const float* __restrict__ scale_x,
                             const float* __restrict__ hist_x,
                             const float* __restrict__ scale_k,
                             const float* __restrict__ hist_k,
                             int hl, float* __restrict__ scales) {
  if (threadIdx.x != 0) return;
  float ax = __uint_as_float(amax[0]);
  for (int i = 0; i < hl - 1; ++i) ax = fmaxf(ax, hist_x[i]);
  float sfx = E4M3_MAX / ax;
  if (!(ax > 0.f && isfinite(ax))) sfx = 1.f / scale_x[0];
  float sx = 1.f / sfx;
  float ak = __uint_as_float(amax[1]);
  for (int i = 0; i < hl - 1; ++i) ak = fmaxf(ak, hist_k[i]);
  float sfk = E4M3_MAX / ak;
  if (!(ak > 0.f && isfinite(ak))) sfk = 1.f / scale_k[0];
  float sk = 1.f / sfk;
  scales[0] = sx;
  scales[1] = sk;
  scales[2] = sx * sk;
}

// Tile layout (both operands), matched to mfma_scale_f32_32x32x64_f8f6f4:
// per (row-block 128 × k-block 64) tile, 8192 B contiguous, as 512 16-B
// chunks c = g*128 + h*64 + l  (g=row-group 0..3, h=k-half 0..1, l=lane):
//   chunk holds op[row = g*32 + (l&31)][k = (l>>5)*32 + h*16 + 0..15]
// => GEMM stages linearly with global_load_lds and reads each lane's
//    32-byte fragment as two conflict-free ds_read_b128 at lane*16.

// ---------------- quantize x -> tiled fp8 A ----------------
__global__ void quant_x_kernel(const float* __restrict__ x,
                               unsigned char* __restrict__ Aq,
                               const float* __restrict__ scales, int K) {
  const float s = scales[0];
  const int kt = blockIdx.x, mt = blockIdx.y, nkt = gridDim.x;
  __shared__ float lt[128][68];
  const int t = threadIdx.x;
  const float* src = x + (size_t)mt * 128 * K + (size_t)kt * 64;
#pragma unroll
  for (int it = 0; it < 8; ++it) {
    int row = it * 16 + (t >> 4);
    int c4 = (t & 15) * 4;
    float4 v = *(const float4*)&src[(size_t)row * K + c4];
    lt[row][c4 + 0] = v.x; lt[row][c4 + 1] = v.y;
    lt[row][c4 + 2] = v.z; lt[row][c4 + 3] = v.w;
  }
  __syncthreads();
  uint4* out = (uint4*)(Aq + ((size_t)mt * nkt + kt) * 8192);
#pragma unroll
  for (int cc = 0; cc < 2; ++cc) {
    int c = t * 2 + cc;
    int g = c >> 7, h = (c >> 6) & 1, l = c & 63;
    int row = g * 32 + (l & 31);
    int kb = (l >> 5) * 32 + h * 16;
    unsigned int w[4];
#pragma unroll
    for (int q = 0; q < 4; ++q) {
      int b = kb + q * 4;
      int p = 0;
      p = __builtin_amdgcn_cvt_pk_fp8_f32(clip448(lt[row][b+0] / s), clip448(lt[row][b+1] / s), p, false);
      p = __builtin_amdgcn_cvt_pk_fp8_f32(clip448(lt[row][b+2] / s), clip448(lt[row][b+3] / s), p, true);
      w[q] = (unsigned int)p;
    }
    out[c] = make_uint4(w[0], w[1], w[2], w[3]);
  }
}

// ---------------- transpose-quantize W[K][N] -> tiled fp8 B ----------------
__global__ void quant_k_kernel(const float* __restrict__ w,
                               unsigned char* __restrict__ Bq,
                               const float* __restrict__ scales, int N) {
  const float s = scales[1];
  const int kt = blockIdx.x, nt = blockIdx.y, nkt = gridDim.x;
  __shared__ float lt[64][132];
  const int t = threadIdx.x;
  const float* src = w + (size_t)kt * 64 * N + (size_t)nt * 128;
#pragma unroll
  for (int it = 0; it < 8; ++it) {
    int row = it * 8 + (t >> 5);
    int c4 = (t & 31) * 4;
    float4 v = *(const float4*)&src[(size_t)row * N + c4];
    lt[row][c4 + 0] = v.x; lt[row][c4 + 1] = v.y;
    lt[row][c4 + 2] = v.z; lt[row][c4 + 3] = v.w;
  }
  __syncthreads();
  uint4* out = (uint4*)(Bq + ((size_t)nt * nkt + kt) * 8192);
#pragma unroll
  for (int cc = 0; cc < 2; ++cc) {
    int c = t * 2 + cc;
    int g = c >> 7, h = (c >> 6) & 1, l = c & 63;
    int nl = g * 32 + (l & 31);
    int kb = (l >> 5) * 32 + h * 16;
    unsigned int w4[4];
#pragma unroll
    for (int q = 0; q < 4; ++q) {
      int b = kb + q * 4;
      int p = 0;
      p = __builtin_amdgcn_cvt_pk_fp8_f32(clip448(lt[b+0][nl] / s), clip448(lt[b+1][nl] / s), p, false);
      p = __builtin_amdgcn_cvt_pk_fp8_f32(clip448(lt[b+2][nl] / s), clip448(lt[b+3][nl] / s), p, true);
      w4[q] = (unsigned int)p;
    }
    out[c] = make_uint4(w4[0], w4[1], w4[2], w4[3]);
  }
}

// ---------------- MX fp8 GEMM + scale + bias + gelu ----------------
// 256x256 tile, BK=64, 512 threads (8 waves, 2M x 4N; per-wave 128x64).
// m201-style phase schedule: each K-tile = 2 phases of
//   {ds_reads ; stage 2 gld_lds ; barrier ; lgkm0 ; setprio1 ; 4 MFMA ; setprio0 ; barrier}
// Triple-buffered LDS (3 x 32 KB); per-tile counted vmcnt(4) waits for a tile
// staged one FULL K-tile earlier (never drains to 0 in steady state).
// Frags are scalar locals (av0..av3,bv0,bv1) — never address-taken (R5 lesson).
#define BUFSZ 32768

#define RD_AV(dst, g_)                                                         \
  {                                                                            \
    const unsigned char* p_ =                                                  \
        lds + cb + ((g_) >> 2) * 8192 + ((g_) & 3) * 2048 + lane * 16;         \
    i32x4 lo_ = *(const i32x4*)p_;                                             \
    i32x4 hi_ = *(const i32x4*)(p_ + 1024);                                    \
    dst = __builtin_shufflevector(lo_, hi_, 0, 1, 2, 3, 4, 5, 6, 7);           \
  }
#define RD_BV(dst, g_)                                                         \
  {                                                                            \
    const unsigned char* p_ =                                                  \
        lds + cb + 16384 + ((g_) >> 2) * 8192 + ((g_) & 3) * 2048 + lane * 16; \
    i32x4 lo_ = *(const i32x4*)p_;                                             \
    i32x4 hi_ = *(const i32x4*)(p_ + 1024);                                    \
    dst = __builtin_shufflevector(lo_, hi_, 0, 1, 2, 3, 4, 5, 6, 7);           \
  }
#define MFMA1(r_, c_, a_, b_)                                                  \
  acc[r_][c_] = __builtin_amdgcn_mfma_scale_f32_32x32x64_f8f6f4(               \
      a_, b_, acc[r_][c_], 0, 0, 0, 127, 0, 127);

__global__ __launch_bounds__(512, 2) void gemm_fp8_kernel(
    const unsigned char* __restrict__ Aq, const unsigned char* __restrict__ Bq,
    const float* __restrict__ bias, const float* __restrict__ scales,
    float* __restrict__ C, int M, int N, int K) {
  __shared__ __align__(16) unsigned char lds[3 * BUFSZ];  // 96 KB
  const float s_xk = scales[2];
  const int nkt = K >> 6;  // 64 for K=4096
  const int t = threadIdx.x;
  const int lane = t & 63;
  const int wid = t >> 6;
  const int wm = wid >> 2, wn = wid & 3;

  // XCD-aware bijective swizzle (nwg = 2048, divisible by 8)
  int f = blockIdx.y * gridDim.x + blockIdx.x;
  int cpx = (gridDim.x * gridDim.y) >> 3;
  int f2 = (f & 7) * cpx + (f >> 3);
  int bx = f2 % gridDim.x;
  int by = f2 / gridDim.x;

  const size_t strideT = (size_t)nkt * 8192;  // one 128-row tile stream
  const unsigned char* gA = Aq + (size_t)(2 * by) * strideT + t * 16;
  const unsigned char* gB = Bq + (size_t)(2 * bx) * strideT + t * 16;

  f32x16 acc[4][2];
#pragma unroll
  for (int i = 0; i < 4; ++i)
#pragma unroll
    for (int j = 0; j < 2; ++j)
#pragma unroll
      for (int r = 0; r < 16; ++r) acc[i][j][r] = 0.f;

  // per-wave stage halves: A = 2 gld_lds, B = 2 gld_lds (4 per tile total)
  auto stageA = [&](unsigned bufbase, int kt_) {
    size_t o = (size_t)kt_ * 8192;
    unsigned char* l = lds + bufbase + wid * 1024;
    gld_lds16(gA + o,           l);            // A rows 0-127
    gld_lds16(gA + strideT + o, l + 8192);     // A rows 128-255
  };
  auto stageB = [&](unsigned bufbase, int kt_) {
    size_t o = (size_t)kt_ * 8192;
    unsigned char* l = lds + bufbase + 16384 + wid * 1024;
    gld_lds16(gB + o,           l);            // B rows 0-127
    gld_lds16(gB + strideT + o, l + 8192);     // B rows 128-255
  };

  i32x8 av0, av1, av2, av3, bv0, bv1;

  // prologue: stage tiles 0 and 1
  stageA(0, 0); stageB(0, 0);
  stageA(BUFSZ, 1); stageB(BUFSZ, 1);
  asm volatile("s_waitcnt vmcnt(4)" ::: "memory");  // tile0 landed; tile1 in flight
  __builtin_amdgcn_s_barrier();

  unsigned cb = 0;  // current buffer byte-offset
  for (int kt = 0; kt < nkt; ++kt) {
    unsigned sb = cb + 2 * BUFSZ;
    if (sb >= 3 * BUFSZ) sb -= 3 * BUFSZ;
    const bool st = (kt + 2 < nkt);

    // ---- phase 1: av0,av1,bv0,bv1 ; stage A(kt+2) ; 4 MFMA (rows 0,1)
    RD_AV(av0, wm * 4 + 0);
    RD_AV(av1, wm * 4 + 1);
    RD_BV(bv0, wn * 2 + 0);
    RD_BV(bv1, wn * 2 + 1);
    if (st) stageA(sb, kt + 2);
    __builtin_amdgcn_s_barrier();
    asm volatile("s_waitcnt lgkmcnt(0)" ::: "memory");
    __builtin_amdgcn_s_setprio(1);
    MFMA1(0, 0, av0, bv0); MFMA1(0, 1, av0, bv1);
    MFMA1(1, 0, av1, bv0); MFMA1(1, 1, av1, bv1);
    __builtin_amdgcn_s_setprio(0);
    __builtin_amdgcn_s_barrier();

    // ---- phase 2: av2,av3 ; stage B(kt+2) ; vmcnt(tile kt+1) ; 4 MFMA (rows 2,3)
    RD_AV(av2, wm * 4 + 2);
    RD_AV(av3, wm * 4 + 3);
    if (st) {
      stageB(sb, kt + 2);
      asm volatile("s_waitcnt vmcnt(4)" ::: "memory");  // tile kt+1 landed
    } else if (kt + 1 < nkt) {
      asm volatile("s_waitcnt vmcnt(0)" ::: "memory");
    }
    __builtin_amdgcn_s_barrier();
    asm volatile("s_waitcnt lgkmcnt(0)" ::: "memory");
    __builtin_amdgcn_s_setprio(1);
    MFMA1(2, 0, av2, bv0); MFMA1(2, 1, av2, bv1);
    MFMA1(3, 0, av3, bv0); MFMA1(3, 1, av3, bv1);
    __builtin_amdgcn_s_setprio(0);
    __builtin_amdgcn_s_barrier();

    cb += BUFSZ;
    if (cb == 3 * BUFSZ) cb = 0;
  }

  // epilogue: scale, bias (bf16-rounded), fast tanh-gelu, nontemporal store
  const int m0 = by * 256;
  const int n0 = bx * 256;
  float bb[2];
#pragma unroll
  for (int j = 0; j < 2; ++j) {
    int col = n0 + wn * 64 + j * 32 + (lane & 31);
    bb[j] = __bfloat162float(__float2bfloat16(bias[col]));
  }
#pragma unroll
  for (int i = 0; i < 4; ++i) {
    int rowbase = m0 + wm * 128 + i * 32 + 4 * (lane >> 5);
#pragma unroll
    for (int j = 0; j < 2; ++j) {
      int col = n0 + wn * 64 + j * 32 + (lane & 31);
#pragma unroll
      for (int r = 0; r < 16; ++r) {
        int row = rowbase + (r & 3) + 8 * (r >> 2);
        float v = acc[i][j][r] * s_xk + bb[j];
        __builtin_nontemporal_store(gelu_f(v), &C[(size_t)row * N + col]);
      }
    }
  }
}

// ---------------- launch ----------------
extern "C" void kernel_launch(void* const* d_in, const int* in_sizes, int n_in,
                              void* d_out, int out_size, void* d_ws, size_t ws_size,
                              hipStream_t stream) {
  const float* inputs = (const float*)d_in[0];
  const float* kernelw = (const float*)d_in[1];
  const float* bias = (const float*)d_in[2];
  const float* input_scale = (const float*)d_in[3];
  const float* input_hist = (const float*)d_in[4];
  const float* kernel_scale = (const float*)d_in[5];
  const float* kernel_hist = (const float*)d_in[6];

  const int F = in_sizes[2];             // 16384
  const int D = in_sizes[1] / F;         // 4096
  const long M = (long)in_sizes[0] / D;  // 8192
  const int HL = in_sizes[4];            // 16
  const int N = F, K = D;

  unsigned int* amax = (unsigned int*)d_ws;
  float* scales = (float*)((char*)d_ws + 16);
  unsigned char* Aq = (unsigned char*)d_ws + 64;
  unsigned char* Bq = Aq + (size_t)M * K;

  float* C = (float*)d_out;

  init_ws_kernel<<<1, 1, 0, stream>>>(amax);
  amax_kernel<<<2048, 256, 0, stream>>>(inputs, (long)M * K / 4, &amax[0]);
  amax_kernel<<<2048, 256, 0, stream>>>(kernelw, (long)K * N / 4, &amax[1]);
  scale_kernel<<<1, 64, 0, stream>>>(amax, input_scale, input_hist, kernel_scale,
                                     kernel_hist, HL, scales);
  quant_x_kernel<<<dim3(K / 64, M / 128), 256, 0, stream>>>(inputs, Aq, scales, K);
  quant_k_kernel<<<dim3(K / 64, N / 128), 256, 0, stream>>>(kernelw, Bq, scales, N);
  gemm_fp8_kernel<<<dim3(N / 256, M / 256), 512, 0, stream>>>(Aq, Bq, bias, scales, C,
                                                              (int)M, N, K);
}

// Round 8
// 728.838 us; speedup vs baseline: 6.0929x; 1.0379x over previous
//
#include <hip/hip_runtime.h>
#include <hip/hip_bf16.h>

typedef __attribute__((ext_vector_type(4))) int i32x4;
typedef __attribute__((ext_vector_type(8))) int i32x8;
typedef __attribute__((ext_vector_type(16))) float f32x16;

#define E4M3_MAX 448.0f
#define AS1 __attribute__((address_space(1)))
#define AS3 __attribute__((address_space(3)))

__device__ __forceinline__ float clip448(float v) {
  return fminf(fmaxf(v, -E4M3_MAX), E4M3_MAX);
}

__device__ __forceinline__ void gld_lds16(const void* g, void* l) {
  __builtin_amdgcn_global_load_lds((const AS1 void*)g, (AS3 void*)l, 16, 0, 0);
}

__device__ __forceinline__ float gelu_f(float v) {
  float y = 0.7978845608028654f * (v + 0.044715f * v * v * v);
  float a = fabsf(y);
  float z = __expf(-2.f * a);          // z in (0,1], no overflow
  float th = (1.f - z) / (1.f + z);    // tanh(|y|)
  th = copysignf(th, y);
  return 0.5f * v * (1.f + th);
}

// ---------------- init ----------------
__global__ void init_ws_kernel(unsigned int* amax) {
  amax[0] = 0u;
  amax[1] = 0u;
}

// ---------------- amax reduction ----------------
__global__ void amax_kernel(const float* __restrict__ x, long n4,
                            unsigned int* __restrict__ amax_out) {
  long i0 = (long)blockIdx.x * blockDim.x + threadIdx.x;
  long stride = (long)gridDim.x * blockDim.x;
  const float4* x4 = (const float4*)x;
  float m = 0.f;
  for (long i = i0; i < n4; i += stride) {
    float4 v = x4[i];
    m = fmaxf(m, fmaxf(fmaxf(fabsf(v.x), fabsf(v.y)), fmaxf(fabsf(v.z), fabsf(v.w))));
  }
#pragma unroll
  for (int off = 32; off >= 1; off >>= 1)
    m = fmaxf(m, __shfl_xor(m, off));
  __shared__ float wmax[8];
  int wid = threadIdx.x >> 6;
  if ((threadIdx.x & 63) == 0) wmax[wid] = m;
  __syncthreads();
  if (threadIdx.x == 0) {
    int nw = blockDim.x >> 6;
    float bm = wmax[0];
    for (int w = 1; w < nw; ++w) bm = fmaxf(bm, wmax[w]);
    atomicMax(amax_out, __float_as_uint(bm));  // vals >= 0: uint order == float order
  }
}

// ---------------- delayed-scaling scale computation ----------------
__global__ void scale_kernel(const unsigned int* __restrict__ amax,
                             const float* __restrict__ scale_x,
                             const float* __restrict__ hist_x,
                             const float* __restrict__ scale_k,
                             const float* __restrict__ hist_k,
                             int hl, float* __restrict__ scales) {
  if (threadIdx.x != 0) return;
  float ax = __uint_as_float(amax[0]);
  for (int i = 0; i < hl - 1; ++i) ax = fmaxf(ax, hist_x[i]);
  float sfx = E4M3_MAX / ax;
  if (!(ax > 0.f && isfinite(ax))) sfx = 1.f / scale_x[0];
  float sx = 1.f / sfx;
  float ak = __uint_as_float(amax[1]);
  for (int i = 0; i < hl - 1; ++i) ak = fmaxf(ak, hist_k[i]);
  float sfk = E4M3_MAX / ak;
  if (!(ak > 0.f && isfinite(ak))) sfk = 1.f / scale_k[0];
  float sk = 1.f / sfk;
  scales[0] = sx;
  scales[1] = sk;
  scales[2] = sx * sk;
}

// Tile layout (both operands), matched to mfma_scale_f32_32x32x64_f8f6f4:
// per (row-block 128 × k-block 64) tile, 8192 B contiguous, as 512 16-B
// chunks c = g*128 + h*64 + l  (g=row-group 0..3, h=k-half 0..1, l=lane):
//   chunk holds op[row = g*32 + (l&31)][k = (l>>5)*32 + h*16 + 0..15]
// => GEMM stages linearly with global_load_lds and reads each lane's
//    32-byte fragment as two conflict-free ds_read_b128 at lane*16.

// ---------------- quantize x -> tiled fp8 A ----------------
__global__ void quant_x_kernel(const float* __restrict__ x,
                               unsigned char* __restrict__ Aq,
                               const float* __restrict__ scales, int K) {
  const float s = scales[0];
  const int kt = blockIdx.x, mt = blockIdx.y, nkt = gridDim.x;
  __shared__ float lt[128][68];
  const int t = threadIdx.x;
  const float* src = x + (size_t)mt * 128 * K + (size_t)kt * 64;
#pragma unroll
  for (int it = 0; it < 8; ++it) {
    int row = it * 16 + (t >> 4);
    int c4 = (t & 15) * 4;
    float4 v = *(const float4*)&src[(size_t)row * K + c4];
    lt[row][c4 + 0] = v.x; lt[row][c4 + 1] = v.y;
    lt[row][c4 + 2] = v.z; lt[row][c4 + 3] = v.w;
  }
  __syncthreads();
  uint4* out = (uint4*)(Aq + ((size_t)mt * nkt + kt) * 8192);
#pragma unroll
  for (int cc = 0; cc < 2; ++cc) {
    int c = t * 2 + cc;
    int g = c >> 7, h = (c >> 6) & 1, l = c & 63;
    int row = g * 32 + (l & 31);
    int kb = (l >> 5) * 32 + h * 16;
    unsigned int w[4];
#pragma unroll
    for (int q = 0; q < 4; ++q) {
      int b = kb + q * 4;
      int p = 0;
      p = __builtin_amdgcn_cvt_pk_fp8_f32(clip448(lt[row][b+0] / s), clip448(lt[row][b+1] / s), p, false);
      p = __builtin_amdgcn_cvt_pk_fp8_f32(clip448(lt[row][b+2] / s), clip448(lt[row][b+3] / s), p, true);
      w[q] = (unsigned int)p;
    }
    out[c] = make_uint4(w[0], w[1], w[2], w[3]);
  }
}

// ---------------- transpose-quantize W[K][N] -> tiled fp8 B ----------------
__global__ void quant_k_kernel(const float* __restrict__ w,
                               unsigned char* __restrict__ Bq,
                               const float* __restrict__ scales, int N) {
  const float s = scales[1];
  const int kt = blockIdx.x, nt = blockIdx.y, nkt = gridDim.x;
  __shared__ float lt[64][132];
  const int t = threadIdx.x;
  const float* src = w + (size_t)kt * 64 * N + (size_t)nt * 128;
#pragma unroll
  for (int it = 0; it < 8; ++it) {
    int row = it * 8 + (t >> 5);
    int c4 = (t & 31) * 4;
    float4 v = *(const float4*)&src[(size_t)row * N + c4];
    lt[row][c4 + 0] = v.x; lt[row][c4 + 1] = v.y;
    lt[row][c4 + 2] = v.z; lt[row][c4 + 3] = v.w;
  }
  __syncthreads();
  uint4* out = (uint4*)(Bq + ((size_t)nt * nkt + kt) * 8192);
#pragma unroll
  for (int cc = 0; cc < 2; ++cc) {
    int c = t * 2 + cc;
    int g = c >> 7, h = (c >> 6) & 1, l = c & 63;
    int nl = g * 32 + (l & 31);
    int kb = (l >> 5) * 32 + h * 16;
    unsigned int w4[4];
#pragma unroll
    for (int q = 0; q < 4; ++q) {
      int b = kb + q * 4;
      int p = 0;
      p = __builtin_amdgcn_cvt_pk_fp8_f32(clip448(lt[b+0][nl] / s), clip448(lt[b+1][nl] / s), p, false);
      p = __builtin_amdgcn_cvt_pk_fp8_f32(clip448(lt[b+2][nl] / s), clip448(lt[b+3][nl] / s), p, true);
      w4[q] = (unsigned int)p;
    }
    out[c] = make_uint4(w4[0], w4[1], w4[2], w4[3]);
  }
}

// ---------------- MX fp8 GEMM + scale + bias + gelu ----------------
// 256x256 tile, BK=64, 512 threads (8 waves, 2M x 4N; per-wave 128x64).
// Minimal-sync schedule (m97-style): per K-tile exactly ONE counted vmcnt +
// ONE barrier; ds_reads and MFMAs listed plainly so the compiler emits
// fine-grained lgkmcnt waits and overlaps MFMA drain with the read stream.
// 4 LDS buffers (128 KB): with a single barrier per tile the max wave skew is
// one iteration, so stage(kt+3) (fast wave) may run concurrently with
// reads(kt) (slow wave) — (kt+3)%4 != kt%4 keeps them disjoint (mod-3 would
// collide). Frags are scalar locals, never address-taken (R5 lesson).
#define BUFSZ 32768

#define RD_AV(dst, g_)                                                         \
  {                                                                            \
    const unsigned char* p_ =                                                  \
        lds + cb + ((g_) >> 2) * 8192 + ((g_) & 3) * 2048 + lane * 16;         \
    i32x4 lo_ = *(const i32x4*)p_;                                             \
    i32x4 hi_ = *(const i32x4*)(p_ + 1024);                                    \
    dst = __builtin_shufflevector(lo_, hi_, 0, 1, 2, 3, 4, 5, 6, 7);           \
  }
#define RD_BV(dst, g_)                                                         \
  {                                                                            \
    const unsigned char* p_ =                                                  \
        lds + cb + 16384 + ((g_) >> 2) * 8192 + ((g_) & 3) * 2048 + lane * 16; \
    i32x4 lo_ = *(const i32x4*)p_;                                             \
    i32x4 hi_ = *(const i32x4*)(p_ + 1024);                                    \
    dst = __builtin_shufflevector(lo_, hi_, 0, 1, 2, 3, 4, 5, 6, 7);           \
  }
#define MFMA1(r_, c_, a_, b_)                                                  \
  acc[r_][c_] = __builtin_amdgcn_mfma_scale_f32_32x32x64_f8f6f4(               \
      a_, b_, acc[r_][c_], 0, 0, 0, 127, 0, 127);

__global__ __launch_bounds__(512, 2) void gemm_fp8_kernel(
    const unsigned char* __restrict__ Aq, const unsigned char* __restrict__ Bq,
    const float* __restrict__ bias, const float* __restrict__ scales,
    float* __restrict__ C, int M, int N, int K) {
  __shared__ __align__(16) unsigned char lds[4 * BUFSZ];  // 128 KB
  const float s_xk = scales[2];
  const int nkt = K >> 6;  // 64 for K=4096
  const int t = threadIdx.x;
  const int lane = t & 63;
  const int wid = t >> 6;
  const int wm = wid >> 2, wn = wid & 3;

  // XCD-aware bijective swizzle (nwg = 2048, divisible by 8)
  int f = blockIdx.y * gridDim.x + blockIdx.x;
  int cpx = (gridDim.x * gridDim.y) >> 3;
  int f2 = (f & 7) * cpx + (f >> 3);
  int bx = f2 % gridDim.x;
  int by = f2 / gridDim.x;

  const size_t strideT = (size_t)nkt * 8192;  // one 128-row tile stream
  const unsigned char* gA = Aq + (size_t)(2 * by) * strideT + t * 16;
  const unsigned char* gB = Bq + (size_t)(2 * bx) * strideT + t * 16;

  f32x16 acc[4][2];
#pragma unroll
  for (int i = 0; i < 4; ++i)
#pragma unroll
    for (int j = 0; j < 2; ++j)
#pragma unroll
      for (int r = 0; r < 16; ++r) acc[i][j][r] = 0.f;

  // one K-tile stage per wave: 4x gld_lds (A two halves, B two halves)
  auto stage = [&](unsigned bufbase, int kt_) {
    size_t o = (size_t)kt_ * 8192;
    unsigned char* l = lds + bufbase + wid * 1024;
    gld_lds16(gA + o,           l);            // A rows 0-127
    gld_lds16(gA + strideT + o, l + 8192);     // A rows 128-255
    gld_lds16(gB + o,           l + 16384);    // B rows 0-127
    gld_lds16(gB + strideT + o, l + 24576);    // B rows 128-255
  };

  i32x8 av0, av1, av2, av3, bv0, bv1;

  // prologue: stage tiles 0 and 1 (depth-2 prefetch)
  stage(0 * BUFSZ, 0);
  stage(1 * BUFSZ, 1);

  for (int kt = 0; kt < nkt; ++kt) {
    const unsigned cb = (kt & 3) * BUFSZ;

    if (kt + 2 < nkt) {
      stage(((kt + 2) & 3) * BUFSZ, kt + 2);
      asm volatile("s_waitcnt vmcnt(8)" ::: "memory");   // tile kt landed
    } else if (kt + 1 < nkt) {
      asm volatile("s_waitcnt vmcnt(4)" ::: "memory");   // tile kt landed
    } else {
      asm volatile("s_waitcnt vmcnt(0)" ::: "memory");
    }
    __builtin_amdgcn_s_barrier();           // tile kt visible; buf reuse gated
    asm volatile("" ::: "memory");          // keep ds_reads below the barrier

    // reads ordered so the first MFMAs' operands land first; compiler emits
    // fine-grained lgkmcnt and overlaps MFMA drain with remaining reads.
    RD_AV(av0, wm * 4 + 0);
    RD_BV(bv0, wn * 2 + 0);
    RD_BV(bv1, wn * 2 + 1);
    RD_AV(av1, wm * 4 + 1);
    RD_AV(av2, wm * 4 + 2);
    RD_AV(av3, wm * 4 + 3);

    MFMA1(0, 0, av0, bv0); MFMA1(0, 1, av0, bv1);
    MFMA1(1, 0, av1, bv0); MFMA1(1, 1, av1, bv1);
    MFMA1(2, 0, av2, bv0); MFMA1(2, 1, av2, bv1);
    MFMA1(3, 0, av3, bv0); MFMA1(3, 1, av3, bv1);
  }

  // epilogue: scale, bias (bf16-rounded), fast tanh-gelu, nontemporal store
  const int m0 = by * 256;
  const int n0 = bx * 256;
  float bb[2];
#pragma unroll
  for (int j = 0; j < 2; ++j) {
    int col = n0 + wn * 64 + j * 32 + (lane & 31);
    bb[j] = __bfloat162float(__float2bfloat16(bias[col]));
  }
#pragma unroll
  for (int i = 0; i < 4; ++i) {
    int rowbase = m0 + wm * 128 + i * 32 + 4 * (lane >> 5);
#pragma unroll
    for (int j = 0; j < 2; ++j) {
      int col = n0 + wn * 64 + j * 32 + (lane & 31);
#pragma unroll
      for (int r = 0; r < 16; ++r) {
        int row = rowbase + (r & 3) + 8 * (r >> 2);
        float v = acc[i][j][r] * s_xk + bb[j];
        __builtin_nontemporal_store(gelu_f(v), &C[(size_t)row * N + col]);
      }
    }
  }
}

// ---------------- launch ----------------
extern "C" void kernel_launch(void* const* d_in, const int* in_sizes, int n_in,
                              void* d_out, int out_size, void* d_ws, size_t ws_size,
                              hipStream_t stream) {
  const float* inputs = (const float*)d_in[0];
  const float* kernelw = (const float*)d_in[1];
  const float* bias = (const float*)d_in[2];
  const float* input_scale = (const float*)d_in[3];
  const float* input_hist = (const float*)d_in[4];
  const float* kernel_scale = (const float*)d_in[5];
  const float* kernel_hist = (const float*)d_in[6];

  const int F = in_sizes[2];             // 16384
  const int D = in_sizes[1] / F;         // 4096
  const long M = (long)in_sizes[0] / D;  // 8192
  const int HL = in_sizes[4];            // 16
  const int N = F, K = D;

  unsigned int* amax = (unsigned int*)d_ws;
  float* scales = (float*)((char*)d_ws + 16);
  unsigned char* Aq = (unsigned char*)d_ws + 64;
  unsigned char* Bq = Aq + (size_t)M * K;

  float* C = (float*)d_out;

  init_ws_kernel<<<1, 1, 0, stream>>>(amax);
  amax_kernel<<<2048, 256, 0, stream>>>(inputs, (long)M * K / 4, &amax[0]);
  amax_kernel<<<2048, 256, 0, stream>>>(kernelw, (long)K * N / 4, &amax[1]);
  scale_kernel<<<1, 64, 0, stream>>>(amax, input_scale, input_hist, kernel_scale,
                                     kernel_hist, HL, scales);
  quant_x_kernel<<<dim3(K / 64, M / 128), 256, 0, stream>>>(inputs, Aq, scales, K);
  quant_k_kernel<<<dim3(K / 64, N / 128), 256, 0, stream>>>(kernelw, Bq, scales, N);
  gemm_fp8_kernel<<<dim3(N / 256, M / 256), 512, 0, stream>>>(Aq, Bq, bias, scales, C,
                                                              (int)M, N, K);
}